// Round 1
// baseline (273.411 us; speedup 1.0000x reference)
//
#include <hip/hip_runtime.h>
#include <math.h>

#define VOX 262144  // 64^3

__device__ __forceinline__ int clampi(int v, int lo, int hi) {
    return v < lo ? lo : (v > hi ? hi : v);
}

// ---- zero the stats area (bn sum[18], bn sumsq[18], gn sum[4], gn sumsq[4]) ----
__global__ void k_init(float* __restrict__ stats) {
    if (threadIdx.x < 64) stats[threadIdx.x] = 0.f;
}

// ---- transpose feat [8][64][64][64] -> featT [64][64][64][8] ----
__global__ void k_transpose(const float* __restrict__ f, float* __restrict__ ft) {
    int idx = blockIdx.x * 256 + threadIdx.x;  // (ci,z,y,x) read order, coalesced reads
    int x = idx & 63, y = (idx >> 6) & 63, z = (idx >> 12) & 63, ci = idx >> 18;
    ft[(((z * 64 + y) * 64 + x) << 3) + ci] = f[idx];
}

// ---- offset conv (3x3x3, 8 -> 18 channels) + BN sum/sumsq reduction ----
__global__ __launch_bounds__(256) void k_conv_off(
        const float* __restrict__ f, const float* __restrict__ w,
        const float* __restrict__ b, float* __restrict__ offs,
        float* __restrict__ stats) {
    int idx = blockIdx.x * 256 + threadIdx.x;
    int h = idx & 63, wy = (idx >> 6) & 63, d = idx >> 12;

    float acc[18];
#pragma unroll
    for (int c = 0; c < 18; c++) acc[c] = b[c];

    for (int ci = 0; ci < 8; ci++) {
#pragma unroll
        for (int kd = 0; kd < 3; kd++) {
            int dd = d + kd - 1;
#pragma unroll
            for (int kw = 0; kw < 3; kw++) {
                int ww = wy + kw - 1;
#pragma unroll
                for (int kh = 0; kh < 3; kh++) {
                    int hh = h + kh - 1;
                    bool ok = ((unsigned)dd < 64u) & ((unsigned)ww < 64u) & ((unsigned)hh < 64u);
                    float v = 0.f;
                    if (ok) v = f[((ci * 64 + dd) * 64 + ww) * 64 + hh];
                    int kidx = (kd * 3 + kw) * 3 + kh;
                    const float* wp = w + ci * 27 + kidx;   // w[c][ci][kidx], stride 216 over c
#pragma unroll
                    for (int c = 0; c < 18; c++)
                        acc[c] = fmaf(v, wp[c * 216], acc[c]);
                }
            }
        }
    }

#pragma unroll
    for (int c = 0; c < 18; c++) offs[c * VOX + idx] = acc[c];

    __shared__ float ls[36];
    if (threadIdx.x < 36) ls[threadIdx.x] = 0.f;
    __syncthreads();
#pragma unroll
    for (int c = 0; c < 18; c++) {
        float s = acc[c], q = acc[c] * acc[c];
#pragma unroll
        for (int o = 32; o > 0; o >>= 1) {
            s += __shfl_xor(s, o);
            q += __shfl_xor(q, o);
        }
        if ((threadIdx.x & 63) == 0) {
            atomicAdd(&ls[c], s);
            atomicAdd(&ls[18 + c], q);
        }
    }
    __syncthreads();
    if (threadIdx.x < 36) atomicAdd(&stats[threadIdx.x], ls[threadIdx.x]);
}

// ---- main: BN affine + tanh + center-out cumsum + bilinear(z,y) gather + (1,1,9) conv
//      + GroupNorm stats.  Writes pre-GN activations to `out` (d_out as scratch). ----
__global__ __launch_bounds__(256) void k_main(
        const float* __restrict__ ft, const float* __restrict__ offs,
        const float* __restrict__ stats, const float* __restrict__ bn_g,
        const float* __restrict__ bn_b, const float* __restrict__ dw,
        const float* __restrict__ db, float* __restrict__ out,
        float* __restrict__ gstats) {
    int idx = blockIdx.x * 256 + threadIdx.x;
    int h = idx & 63, wy = (idx >> 6) & 63, d = idx >> 12;
    const float inv = 1.f / (float)VOX;

    float zo[9], yo[9];
#pragma unroll
    for (int c = 0; c < 18; c++) {
        float m = stats[c] * inv;
        float var = stats[18 + c] * inv - m * m;
        float rs = rsqrtf(var + 1e-5f);
        float t = tanhf(bn_g[c] * ((offs[c * VOX + idx] - m) * rs) + bn_b[c]);
        if (c < 9) zo[c] = t; else yo[c - 9] = t;
    }

    // cumsum outward from center (K=9, CENTER=4)
    float za[9], ya[9];
    za[4] = zo[4]; ya[4] = yo[4];
#pragma unroll
    for (int k = 5; k < 9; k++) { za[k] = za[k - 1] + zo[k]; ya[k] = ya[k - 1] + yo[k]; }
#pragma unroll
    for (int k = 3; k >= 0; k--) { za[k] = za[k + 1] + zo[k]; ya[k] = ya[k + 1] + yo[k]; }

    float acc[16];
#pragma unroll
    for (int co = 0; co < 16; co++) acc[co] = db[co];

#pragma unroll
    for (int k = 0; k < 9; k++) {
        int xi = h + k - 4;
        // x is exactly integer: weight 1 for xi in [0,62], exactly 0 otherwise
        // (incl. xi==63 where both clipped x-weights vanish).
        if (xi >= 0 && xi <= 62) {
            float z = (float)d + za[k];
            float y = (float)wy + ya[k];
            float fz = floorf(z), fy = floorf(y);
            int iz = (int)fz, iy = (int)fy;
            int z0 = clampi(iz, 0, 63), z1 = clampi(iz + 1, 0, 63);
            int y0 = clampi(iy, 0, 63), y1 = clampi(iy + 1, 0, 63);
            float wz0 = (float)z1 - z, wz1 = z - (float)z0;
            float wy0 = (float)y1 - y, wy1 = y - (float)y0;
            float w00 = wz0 * wy0, w01 = wz0 * wy1, w10 = wz1 * wy0, w11 = wz1 * wy1;

            const float4* p00 = (const float4*)(ft + (((z0 * 64 + y0) * 64 + xi) << 3));
            const float4* p01 = (const float4*)(ft + (((z0 * 64 + y1) * 64 + xi) << 3));
            const float4* p10 = (const float4*)(ft + (((z1 * 64 + y0) * 64 + xi) << 3));
            const float4* p11 = (const float4*)(ft + (((z1 * 64 + y1) * 64 + xi) << 3));
            float4 a00 = p00[0], b00 = p00[1];
            float4 a01 = p01[0], b01 = p01[1];
            float4 a10 = p10[0], b10 = p10[1];
            float4 a11 = p11[0], b11 = p11[1];

            float v[8];
            v[0] = w00 * a00.x + w01 * a01.x + w10 * a10.x + w11 * a11.x;
            v[1] = w00 * a00.y + w01 * a01.y + w10 * a10.y + w11 * a11.y;
            v[2] = w00 * a00.z + w01 * a01.z + w10 * a10.z + w11 * a11.z;
            v[3] = w00 * a00.w + w01 * a01.w + w10 * a10.w + w11 * a11.w;
            v[4] = w00 * b00.x + w01 * b01.x + w10 * b10.x + w11 * b11.x;
            v[5] = w00 * b00.y + w01 * b01.y + w10 * b10.y + w11 * b11.y;
            v[6] = w00 * b00.z + w01 * b01.z + w10 * b10.z + w11 * b11.z;
            v[7] = w00 * b00.w + w01 * b01.w + w10 * b10.w + w11 * b11.w;

#pragma unroll
            for (int ci = 0; ci < 8; ci++) {
#pragma unroll
                for (int co = 0; co < 16; co++)
                    acc[co] = fmaf(v[ci], dw[(co * 8 + ci) * 9 + k], acc[co]);
            }
        }
    }

#pragma unroll
    for (int co = 0; co < 16; co++) out[co * VOX + idx] = acc[co];

    // group-norm stats: 4 groups of 4 channels
    __shared__ float ls[8];
    if (threadIdx.x < 8) ls[threadIdx.x] = 0.f;
    __syncthreads();
#pragma unroll
    for (int g = 0; g < 4; g++) {
        float s = acc[4 * g] + acc[4 * g + 1] + acc[4 * g + 2] + acc[4 * g + 3];
        float q = acc[4 * g] * acc[4 * g] + acc[4 * g + 1] * acc[4 * g + 1]
                + acc[4 * g + 2] * acc[4 * g + 2] + acc[4 * g + 3] * acc[4 * g + 3];
#pragma unroll
        for (int o = 32; o > 0; o >>= 1) {
            s += __shfl_xor(s, o);
            q += __shfl_xor(q, o);
        }
        if ((threadIdx.x & 63) == 0) {
            atomicAdd(&ls[g], s);
            atomicAdd(&ls[4 + g], q);
        }
    }
    __syncthreads();
    if (threadIdx.x < 8) atomicAdd(&gstats[threadIdx.x], ls[threadIdx.x]);
}

// ---- apply GroupNorm + ReLU in place on d_out ----
__global__ void k_gn(const float* __restrict__ gstats, const float* __restrict__ gn_g,
                     const float* __restrict__ gn_b, float* __restrict__ out) {
    int idx = blockIdx.x * 256 + threadIdx.x;  // 16*VOX elements
    int c = idx >> 18;                         // idx / VOX
    int g = c >> 2;
    const float invn = 1.f / (4.f * (float)VOX);
    float m = gstats[g] * invn;
    float var = gstats[4 + g] * invn - m * m;
    float rs = rsqrtf(var + 1e-5f);
    float v = (out[idx] - m) * rs * gn_g[c] + gn_b[c];
    out[idx] = v > 0.f ? v : 0.f;
}

extern "C" void kernel_launch(void* const* d_in, const int* in_sizes, int n_in,
                              void* d_out, int out_size, void* d_ws, size_t ws_size,
                              hipStream_t stream) {
    const float* f    = (const float*)d_in[0];
    const float* offw = (const float*)d_in[1];
    const float* offb = (const float*)d_in[2];
    const float* bng  = (const float*)d_in[3];
    const float* bnb  = (const float*)d_in[4];
    const float* dcnw = (const float*)d_in[5];
    const float* dcnb = (const float*)d_in[6];
    const float* gng  = (const float*)d_in[7];
    const float* gnb  = (const float*)d_in[8];
    float* out = (float*)d_out;

    float* ws    = (float*)d_ws;
    float* ft    = ws;               // 8*VOX floats (featT)
    float* offs  = ws + 8 * VOX;     // 18*VOX floats (raw offset conv)
    float* stats = offs + 18 * VOX;  // 36 bn stats + 8 gn stats
    float* gstats = stats + 36;

    hipLaunchKernelGGL(k_init, dim3(1), dim3(64), 0, stream, stats);
    hipLaunchKernelGGL(k_transpose, dim3((8 * VOX) / 256), dim3(256), 0, stream, f, ft);
    hipLaunchKernelGGL(k_conv_off, dim3(VOX / 256), dim3(256), 0, stream,
                       f, offw, offb, offs, stats);
    hipLaunchKernelGGL(k_main, dim3(VOX / 256), dim3(256), 0, stream,
                       ft, offs, stats, bng, bnb, dcnw, dcnb, out, gstats);
    hipLaunchKernelGGL(k_gn, dim3((16 * VOX) / 256), dim3(256), 0, stream,
                       gstats, gng, gnb, out);
}

// Round 2
// 195.298 us; speedup vs baseline: 1.4000x; 1.4000x over previous
//
#include <hip/hip_runtime.h>
#include <math.h>

#define VOX 262144  // 64^3

__device__ __forceinline__ int clampi(int v, int lo, int hi) {
    return v < lo ? lo : (v > hi ? hi : v);
}

// ---- zero the stats area (bn sum[18], bn sumsq[18], gn sum[4], gn sumsq[4]) ----
__global__ void k_init(float* __restrict__ stats) {
    if (threadIdx.x < 64) stats[threadIdx.x] = 0.f;
}

// ---- weight transpose: w[c][ci][k] (c<18 used) -> wT[k][ci][c], 3888 floats ----
__global__ void k_wt(const float* __restrict__ w, float* __restrict__ wT) {
    int i = blockIdx.x * 256 + threadIdx.x;  // over 18*8*27 = 3888
    if (i < 3888) {
        int c = i / 216, r = i % 216;
        int ci = r / 27, k = r % 27;
        wT[(k * 8 + ci) * 18 + c] = w[i];
    }
}

// ---- transpose feat [8][64][64][64] -> featT [64][64][64][8] ----
__global__ void k_transpose(const float* __restrict__ f, float* __restrict__ ft) {
    int idx = blockIdx.x * 256 + threadIdx.x;  // (ci,z,y,x) read order, coalesced reads
    int x = idx & 63, y = (idx >> 6) & 63, z = (idx >> 12) & 63, ci = idx >> 18;
    ft[(((z * 64 + y) * 64 + x) << 3) + ci] = f[idx];
}

// ---- offset conv (3x3x3, 8 -> 18 channels) + BN sum/sumsq reduction ----
// Fully unrolled; weights from wT at compile-time offsets -> scalar loads.
// (dd,ww) bounds are wave-uniform (wave spans x only) -> scalar branch.
// x bounds via clamp-index + 0/1 multiplier (exact: out-of-range contributes 0).
__global__ __launch_bounds__(256) void k_conv_off(
        const float* __restrict__ f, const float* __restrict__ wT,
        const float* __restrict__ b, float* __restrict__ offs,
        float* __restrict__ stats) {
    int idx = blockIdx.x * 256 + threadIdx.x;
    int h = idx & 63, wy = (idx >> 6) & 63, d = idx >> 12;

    int hc0 = h > 0 ? h - 1 : 0;
    int hc2 = h < 63 ? h + 1 : 63;
    float mh0 = h > 0 ? 1.f : 0.f;
    float mh2 = h < 63 ? 1.f : 0.f;

    float acc[18];
#pragma unroll
    for (int c = 0; c < 18; c++) acc[c] = b[c];

#pragma unroll
    for (int kd = 0; kd < 3; kd++) {
        int dd = d + kd - 1;
#pragma unroll
        for (int kw = 0; kw < 3; kw++) {
            int ww = wy + kw - 1;
            bool ok = ((unsigned)dd < 64u) & ((unsigned)ww < 64u);  // wave-uniform
            const float* fp = f + (dd * 64 + ww) * 64;
            const float* wrow = wT + ((kd * 3 + kw) * 3) * 8 * 18;  // + ci*18 + kh*144 + c
            if (ok) {
#pragma unroll
                for (int ci = 0; ci < 8; ci++) {
                    float v0 = fp[ci * VOX + hc0] * mh0;
                    float v1 = fp[ci * VOX + h];
                    float v2 = fp[ci * VOX + hc2] * mh2;
                    const float* wp = wrow + ci * 18;
#pragma unroll
                    for (int c = 0; c < 18; c++) {
                        float a = acc[c];
                        a = fmaf(v0, wp[c], a);
                        a = fmaf(v1, wp[144 + c], a);
                        a = fmaf(v2, wp[288 + c], a);
                        acc[c] = a;
                    }
                }
            }
        }
    }

#pragma unroll
    for (int c = 0; c < 18; c++) offs[c * VOX + idx] = acc[c];

    __shared__ float ls[36];
    if (threadIdx.x < 36) ls[threadIdx.x] = 0.f;
    __syncthreads();
#pragma unroll
    for (int c = 0; c < 18; c++) {
        float s = acc[c], q = acc[c] * acc[c];
#pragma unroll
        for (int o = 32; o > 0; o >>= 1) {
            s += __shfl_xor(s, o);
            q += __shfl_xor(q, o);
        }
        if ((threadIdx.x & 63) == 0) {
            atomicAdd(&ls[c], s);
            atomicAdd(&ls[18 + c], q);
        }
    }
    __syncthreads();
    if (threadIdx.x < 36) atomicAdd(&stats[threadIdx.x], ls[threadIdx.x]);
}

// ---- main: BN affine + tanh + center-out cumsum + bilinear(z,y) gather + (1,1,9) conv
//      + GroupNorm stats.  Writes pre-GN activations to `out` (d_out as scratch). ----
__global__ __launch_bounds__(256) void k_main(
        const float* __restrict__ ft, const float* __restrict__ offs,
        const float* __restrict__ stats, const float* __restrict__ bn_g,
        const float* __restrict__ bn_b, const float* __restrict__ dw,
        const float* __restrict__ db, float* __restrict__ out,
        float* __restrict__ gstats) {
    int idx = blockIdx.x * 256 + threadIdx.x;
    int h = idx & 63, wy = (idx >> 6) & 63, d = idx >> 12;
    const float inv = 1.f / (float)VOX;

    float zo[9], yo[9];
#pragma unroll
    for (int c = 0; c < 18; c++) {
        float m = stats[c] * inv;
        float var = stats[18 + c] * inv - m * m;
        float rs = rsqrtf(var + 1e-5f);
        float t = tanhf(bn_g[c] * ((offs[c * VOX + idx] - m) * rs) + bn_b[c]);
        if (c < 9) zo[c] = t; else yo[c - 9] = t;
    }

    // cumsum outward from center (K=9, CENTER=4)
    float za[9], ya[9];
    za[4] = zo[4]; ya[4] = yo[4];
#pragma unroll
    for (int k = 5; k < 9; k++) { za[k] = za[k - 1] + zo[k]; ya[k] = ya[k - 1] + yo[k]; }
#pragma unroll
    for (int k = 3; k >= 0; k--) { za[k] = za[k + 1] + zo[k]; ya[k] = ya[k + 1] + yo[k]; }

    float acc[16];
#pragma unroll
    for (int co = 0; co < 16; co++) acc[co] = db[co];

#pragma unroll
    for (int k = 0; k < 9; k++) {
        int xi = h + k - 4;
        // x is exactly integer: weight 1 for xi in [0,62], exactly 0 otherwise
        // (incl. xi==63 where both clipped x-weights vanish).
        if (xi >= 0 && xi <= 62) {
            float z = (float)d + za[k];
            float y = (float)wy + ya[k];
            float fz = floorf(z), fy = floorf(y);
            int iz = (int)fz, iy = (int)fy;
            int z0 = clampi(iz, 0, 63), z1 = clampi(iz + 1, 0, 63);
            int y0 = clampi(iy, 0, 63), y1 = clampi(iy + 1, 0, 63);
            float wz0 = (float)z1 - z, wz1 = z - (float)z0;
            float wy0 = (float)y1 - y, wy1 = y - (float)y0;
            float w00 = wz0 * wy0, w01 = wz0 * wy1, w10 = wz1 * wy0, w11 = wz1 * wy1;

            const float4* p00 = (const float4*)(ft + (((z0 * 64 + y0) * 64 + xi) << 3));
            const float4* p01 = (const float4*)(ft + (((z0 * 64 + y1) * 64 + xi) << 3));
            const float4* p10 = (const float4*)(ft + (((z1 * 64 + y0) * 64 + xi) << 3));
            const float4* p11 = (const float4*)(ft + (((z1 * 64 + y1) * 64 + xi) << 3));
            float4 a00 = p00[0], b00 = p00[1];
            float4 a01 = p01[0], b01 = p01[1];
            float4 a10 = p10[0], b10 = p10[1];
            float4 a11 = p11[0], b11 = p11[1];

            float v[8];
            v[0] = w00 * a00.x + w01 * a01.x + w10 * a10.x + w11 * a11.x;
            v[1] = w00 * a00.y + w01 * a01.y + w10 * a10.y + w11 * a11.y;
            v[2] = w00 * a00.z + w01 * a01.z + w10 * a10.z + w11 * a11.z;
            v[3] = w00 * a00.w + w01 * a01.w + w10 * a10.w + w11 * a11.w;
            v[4] = w00 * b00.x + w01 * b01.x + w10 * b10.x + w11 * b11.x;
            v[5] = w00 * b00.y + w01 * b01.y + w10 * b10.y + w11 * b11.y;
            v[6] = w00 * b00.z + w01 * b01.z + w10 * b10.z + w11 * b11.z;
            v[7] = w00 * b00.w + w01 * b01.w + w10 * b10.w + w11 * b11.w;

#pragma unroll
            for (int ci = 0; ci < 8; ci++) {
#pragma unroll
                for (int co = 0; co < 16; co++)
                    acc[co] = fmaf(v[ci], dw[(co * 8 + ci) * 9 + k], acc[co]);
            }
        }
    }

#pragma unroll
    for (int co = 0; co < 16; co++) out[co * VOX + idx] = acc[co];

    // group-norm stats: 4 groups of 4 channels
    __shared__ float ls[8];
    if (threadIdx.x < 8) ls[threadIdx.x] = 0.f;
    __syncthreads();
#pragma unroll
    for (int g = 0; g < 4; g++) {
        float s = acc[4 * g] + acc[4 * g + 1] + acc[4 * g + 2] + acc[4 * g + 3];
        float q = acc[4 * g] * acc[4 * g] + acc[4 * g + 1] * acc[4 * g + 1]
                + acc[4 * g + 2] * acc[4 * g + 2] + acc[4 * g + 3] * acc[4 * g + 3];
#pragma unroll
        for (int o = 32; o > 0; o >>= 1) {
            s += __shfl_xor(s, o);
            q += __shfl_xor(q, o);
        }
        if ((threadIdx.x & 63) == 0) {
            atomicAdd(&ls[g], s);
            atomicAdd(&ls[4 + g], q);
        }
    }
    __syncthreads();
    if (threadIdx.x < 8) atomicAdd(&gstats[threadIdx.x], ls[threadIdx.x]);
}

// ---- apply GroupNorm + ReLU in place on d_out ----
__global__ void k_gn(const float* __restrict__ gstats, const float* __restrict__ gn_g,
                     const float* __restrict__ gn_b, float* __restrict__ out) {
    int idx = blockIdx.x * 256 + threadIdx.x;  // 16*VOX elements
    int c = idx >> 18;                         // idx / VOX
    int g = c >> 2;
    const float invn = 1.f / (4.f * (float)VOX);
    float m = gstats[g] * invn;
    float var = gstats[4 + g] * invn - m * m;
    float rs = rsqrtf(var + 1e-5f);
    float v = (out[idx] - m) * rs * gn_g[c] + gn_b[c];
    out[idx] = v > 0.f ? v : 0.f;
}

extern "C" void kernel_launch(void* const* d_in, const int* in_sizes, int n_in,
                              void* d_out, int out_size, void* d_ws, size_t ws_size,
                              hipStream_t stream) {
    const float* f    = (const float*)d_in[0];
    const float* offw = (const float*)d_in[1];
    const float* offb = (const float*)d_in[2];
    const float* bng  = (const float*)d_in[3];
    const float* bnb  = (const float*)d_in[4];
    const float* dcnw = (const float*)d_in[5];
    const float* dcnb = (const float*)d_in[6];
    const float* gng  = (const float*)d_in[7];
    const float* gnb  = (const float*)d_in[8];
    float* out = (float*)d_out;

    float* ws    = (float*)d_ws;
    float* ft    = ws;               // 8*VOX floats (featT)
    float* offs  = ws + 8 * VOX;     // 18*VOX floats (raw offset conv)
    float* stats = offs + 18 * VOX;  // 36 bn stats + 8 gn stats
    float* gstats = stats + 36;
    // wT lives in d_out's first 3888 floats: dead until k_main overwrites out.
    float* wT = out;

    hipLaunchKernelGGL(k_init, dim3(1), dim3(64), 0, stream, stats);
    hipLaunchKernelGGL(k_wt, dim3(16), dim3(256), 0, stream, offw, wT);
    hipLaunchKernelGGL(k_transpose, dim3((8 * VOX) / 256), dim3(256), 0, stream, f, ft);
    hipLaunchKernelGGL(k_conv_off, dim3(VOX / 256), dim3(256), 0, stream,
                       f, wT, offb, offs, stats);
    hipLaunchKernelGGL(k_main, dim3(VOX / 256), dim3(256), 0, stream,
                       ft, offs, stats, bng, bnb, dcnw, dcnb, out, gstats);
    hipLaunchKernelGGL(k_gn, dim3((16 * VOX) / 256), dim3(256), 0, stream,
                       gstats, gng, gnb, out);
}